// Round 2
// baseline (539.826 us; speedup 1.0000x reference)
//
#include <hip/hip_runtime.h>
#include <hip/hip_fp16.h>

// Problem constants (fixed-shape problem)
#define TOK  64
#define INF  4096
#define OUTF 11008
// numel = OUTF*INF = 45088768; quant block = 1024 -> scale idx = pos >> 10

// Harness dtype conventions: float16 inputs arrive as fp32 (only bf16/fp32/int
// are native); integers arrive as int32; output (fp16 in reference) is fp32.
typedef __attribute__((ext_vector_type(8))) _Float16 half8;
typedef __attribute__((ext_vector_type(4))) float floatx4;
typedef __attribute__((ext_vector_type(8))) unsigned short ushort8;

// ---------------------------------------------------------------------------
// Kernel 1: dequantize int8 values -> W (fp16), scatter by int8_pos.
// block_idx input is redundant (pos >> 10), never read (-180 MB traffic).
// ---------------------------------------------------------------------------
__global__ __launch_bounds__(256) void dequant_i8_kernel(
    const int* __restrict__ data, const int* __restrict__ pos,
    const float* __restrict__ scales, _Float16* __restrict__ W, int n) {
  int i = blockIdx.x * 256 + threadIdx.x;
  const int stride = gridDim.x * 256;
  for (; i < n; i += stride) {
    const int p = pos[i];
    W[p] = (_Float16)((float)data[i] * scales[p >> 10]);
  }
}

// ---------------------------------------------------------------------------
// Kernel 2: scatter fp32(->fp16) outliers into W. Outlier + int8 positions
// exactly partition [0, numel), so W needs no zero-init.
// ---------------------------------------------------------------------------
__global__ __launch_bounds__(256) void scatter_out_kernel(
    const float* __restrict__ vals, const int* __restrict__ pos,
    _Float16* __restrict__ W, int n) {
  const int i = blockIdx.x * 256 + threadIdx.x;
  if (i < n) W[pos[i]] = (_Float16)vals[i];
}

// ---------------------------------------------------------------------------
// Kernel 3: out = x @ W^T + bias.  x: (64,4096) fp32 row-major (converted to
// fp16 during LDS staging), W: (11008,4096) fp16 row-major -> NT GEMM.
// Grid: 688 blocks, each computes the full-M 64 x 16(N) strip over full K.
// 256 threads = 4 waves; wave w owns M rows [16w, 16w+16).
// mfma_f32_16x16x32_f16; A-frag: m=lane&15, k=quad*8+j; B-frag: n=lane&15,
// k=quad*8+j; D: row(m)=quad*4+reg, col(n)=lane&15.
// ---------------------------------------------------------------------------
__global__ __launch_bounds__(256) void gemm_kernel(
    const float* __restrict__ x, const _Float16* __restrict__ W,
    const float* __restrict__ bias, float* __restrict__ out) {
  __shared__ __align__(16) _Float16 As[64 * 64];  // [m][k]
  __shared__ __align__(16) _Float16 Bs[16 * 64];  // [n][k]

  const int tid  = threadIdx.x;
  const int wave = tid >> 6;
  const int lane = tid & 63;
  const int n0   = blockIdx.x * 16;

  floatx4 acc = {0.f, 0.f, 0.f, 0.f};

  const int arow = wave * 16 + (lane & 15);  // M row of this lane's A-frag
  const int brow = lane & 15;                // N row of this lane's B-frag
  const int koff = (lane >> 4) * 8;          // quad*8 within the K=32 slab

  for (int k0 = 0; k0 < INF; k0 += 64) {
    // Stage A: 64 rows x 64 K fp32 -> fp16. 512 8-elem chunks, 2 per thread.
#pragma unroll
    for (int it = 0; it < 2; ++it) {
      const int c = tid + it * 256;
      const int r = c >> 3, cc = (c & 7) * 8;
      const floatx4 f0 = *(const floatx4*)&x[r * INF + k0 + cc];
      const floatx4 f1 = *(const floatx4*)&x[r * INF + k0 + cc + 4];
      half8 h;
      h[0] = (_Float16)f0[0]; h[1] = (_Float16)f0[1];
      h[2] = (_Float16)f0[2]; h[3] = (_Float16)f0[3];
      h[4] = (_Float16)f1[0]; h[5] = (_Float16)f1[1];
      h[6] = (_Float16)f1[2]; h[7] = (_Float16)f1[3];
      *(half8*)&As[r * 64 + cc] = h;
    }
    // Stage B: 16 rows x 64 K fp16 copy — 128 16B chunks, first 128 threads.
    if (tid < 128) {
      const int r = tid >> 3, cc = (tid & 7) * 8;
      *(ushort8*)&Bs[r * 64 + cc] =
          *(const ushort8*)&W[(n0 + r) * INF + k0 + cc];
    }
    __syncthreads();
#pragma unroll
    for (int kk = 0; kk < 64; kk += 32) {
      half8 a = *(const half8*)&As[arow * 64 + kk + koff];
      half8 b = *(const half8*)&Bs[brow * 64 + kk + koff];
      acc = __builtin_amdgcn_mfma_f32_16x16x32_f16(a, b, acc, 0, 0, 0);
    }
    __syncthreads();
  }

  // Epilogue: add bias, store fp32. Lane holds C[quad*4+i][lane&15].
  const int n    = n0 + (lane & 15);
  const int quad = lane >> 4;
  const float bv = bias[n];
#pragma unroll
  for (int i = 0; i < 4; ++i) {
    const int t = wave * 16 + quad * 4 + i;
    out[t * OUTF + n] = acc[i] + bv;
  }
}

// ---------------------------------------------------------------------------
// Launch. Inputs (setup_inputs order):
// 0 x(fp32, 64*4096) 1 int8_data(int32) 2 fp16_data(fp32) 3 scales(fp32,44032)
// 4 bias(fp32,11008) 5 int8_pos(int32) 6 fp16_pos(int32) 7 block_idx(unused)
// ws: W fp16, 45088768 elems = 90.2 MB.
// ---------------------------------------------------------------------------
extern "C" void kernel_launch(void* const* d_in, const int* in_sizes, int n_in,
                              void* d_out, int out_size, void* d_ws,
                              size_t ws_size, hipStream_t stream) {
  const float* x         = (const float*)d_in[0];
  const int*   int8_data = (const int*)d_in[1];
  const float* fp16_data = (const float*)d_in[2];
  const float* scales    = (const float*)d_in[3];
  const float* bias      = (const float*)d_in[4];
  const int*   int8_pos  = (const int*)d_in[5];
  const int*   fp16_pos  = (const int*)d_in[6];
  // d_in[7] = block_idx (unused; redundant with pos >> 10)

  _Float16* W   = (_Float16*)d_ws;
  float*    out = (float*)d_out;

  const int n8 = in_sizes[1];
  const int nf = in_sizes[2];

  dequant_i8_kernel<<<4096, 256, 0, stream>>>(int8_data, int8_pos, scales, W, n8);
  scatter_out_kernel<<<(nf + 255) / 256, 256, 0, stream>>>(fp16_data, fp16_pos, W, nf);
  gemm_kernel<<<OUTF / 16, 256, 0, stream>>>(x, W, bias, out);
}